// Round 3
// baseline (500.201 us; speedup 1.0000x reference)
//
#include <hip/hip_runtime.h>
#include <math.h>

// Inputs fp32, output buffer fp32 (verified by round-1/2 error forensics).
// Internal compute fp32.

__device__ __forceinline__ float sigf(float x) { return 1.0f / (1.0f + expf(-x)); }

__device__ __forceinline__ float wave_red(float v) {
#pragma unroll
    for (int s = 32; s; s >>= 1) v += __shfl_down(v, s, 64);
    return v;
}

// dot of 1024 fp32 weights with 1024 fp32 x, one 64-lane wave, lane-contiguous float4s
__device__ __forceinline__ float dotf(const float* __restrict__ w,
                                      const float* __restrict__ x, int lane) {
    float acc = 0.f;
#pragma unroll
    for (int j = 0; j < 4; ++j) {
        float4 a = *reinterpret_cast<const float4*>(w + j * 256 + lane * 4);
        float4 b = *reinterpret_cast<const float4*>(x + j * 256 + lane * 4);
        acc += a.x * b.x + a.y * b.y + a.z * b.z + a.w * b.w;
    }
    return acc;
}

// ---------------- column max over tsn [4096,1024] ----------------
__global__ void colmax_part_k(const float* __restrict__ tsn, float* __restrict__ part) {
    int tid = threadIdx.x;
    const float4* t4 = reinterpret_cast<const float4*>(tsn);
    float4 m = make_float4(-INFINITY, -INFINITY, -INFINITY, -INFINITY);
    int r0 = blockIdx.x * 512;
    for (int r = r0; r < r0 + 512; ++r) {
        float4 v = t4[(size_t)r * 256 + tid];
        m.x = fmaxf(m.x, v.x); m.y = fmaxf(m.y, v.y);
        m.z = fmaxf(m.z, v.z); m.w = fmaxf(m.w, v.w);
    }
    reinterpret_cast<float4*>(part + (size_t)blockIdx.x * 1024)[tid] = m;
}
__global__ void colmax_fin_k(const float* __restrict__ part, float* __restrict__ maxv) {
    int c = blockIdx.x * 256 + threadIdx.x;
    float m = -INFINITY;
    for (int b = 0; b < 8; ++b) m = fmaxf(m, part[b * 1024 + c]);
    maxv[c] = m;
}

// ---------------- generic GEMV: y[r] = segA + segB + b1 + b2 ----------------
__global__ void gemv_k(const float* __restrict__ W, int ld, int nrows,
                       const float* __restrict__ xA, int offA,
                       const float* __restrict__ xB, int offB,
                       const float* __restrict__ b1,
                       const float* __restrict__ b2,
                       float* __restrict__ yF, float* __restrict__ yOut) {
    int wave = threadIdx.x >> 6, lane = threadIdx.x & 63;
    int row = blockIdx.x * 4 + wave;
    if (row >= nrows) return;
    const float* wr = W + (size_t)row * ld;
    float acc = 0.f;
    if (xA) acc += dotf(wr + offA, xA, lane);
    if (xB) acc += dotf(wr + offB, xB, lane);
    acc = wave_red(acc);
    if (lane == 0) {
        if (b1) acc += b1[row];
        if (b2) acc += b2[row];
        if (yF) yF[row] = acc;
        if (yOut) yOut[row] = acc;
    }
}

// ---------------- fused gates-GEMV + LSTM cell ----------------
// Block b handles j in [4b, 4b+4). Wave w computes gate-w rows (row = w*1024+j).
__global__ void lstm_fused_k(const float* __restrict__ W, int ld, int off,
                             const float* __restrict__ x,
                             const float* __restrict__ b1,
                             const float* __restrict__ b2,
                             const float* __restrict__ gx,
                             const float* __restrict__ cc_in,
                             float* __restrict__ cc_out,
                             float* __restrict__ h_out) {
    __shared__ float glds[4][4];
    int wave = threadIdx.x >> 6, lane = threadIdx.x & 63;
    int j0 = blockIdx.x * 4;
#pragma unroll
    for (int jj = 0; jj < 4; ++jj) {
        int row = wave * 1024 + j0 + jj;
        float acc = dotf(W + (size_t)row * ld + off, x, lane);
        acc = wave_red(acc);
        if (lane == 0) {
            if (b1) acc += b1[row];
            if (b2) acc += b2[row];
            if (gx) acc += gx[row];
            glds[wave][jj] = acc;
        }
    }
    __syncthreads();
    if (threadIdx.x < 4) {
        int jj = threadIdx.x, j = j0 + jj;
        float gi = glds[0][jj], gf = glds[1][jj], gg = glds[2][jj], go = glds[3][jj];
        float c = sigf(gi) * tanhf(gg);
        if (cc_in) c += sigf(gf) * cc_in[j];
        float h = sigf(go) * tanhf(c);
        if (cc_out) cc_out[j] = c;
        h_out[j] = h;
    }
}

// zero-state cell straight from precomputed gates gx (step t=0 of expansions)
__global__ void cell0_k(const float* __restrict__ gx, float* __restrict__ cc_out,
                        float* __restrict__ h_out) {
    int j = blockIdx.x * 256 + threadIdx.x;
    float gi = gx[j], gg = gx[2048 + j], go = gx[3072 + j];
    float c = sigf(gi) * tanhf(gg);
    float h = sigf(go) * tanhf(c);
    cc_out[j] = c;
    h_out[j] = h;
}

// nfs[t][i] = relu(sv[i] + dot(Wp[i, 1024:2048], a_js[t])), t=0..9
__global__ void nfs_k(const float* __restrict__ Wp, const float* __restrict__ ajs,
                      const float* __restrict__ sv, float* __restrict__ nfs) {
    int wave = threadIdx.x >> 6, lane = threadIdx.x & 63;
    int i = blockIdx.x * 4 + wave;
    const float* wr = Wp + (size_t)i * 3072 + 1024;
    float wf[16];
#pragma unroll
    for (int j = 0; j < 4; ++j) {
        float4 a = *reinterpret_cast<const float4*>(wr + j * 256 + lane * 4);
        wf[j * 4 + 0] = a.x; wf[j * 4 + 1] = a.y; wf[j * 4 + 2] = a.z; wf[j * 4 + 3] = a.w;
    }
    float acc[10];
#pragma unroll
    for (int t = 0; t < 10; ++t) acc[t] = 0.f;
#pragma unroll
    for (int t = 0; t < 10; ++t) {
        const float* a = ajs + t * 1024;
#pragma unroll
        for (int j = 0; j < 4; ++j) {
            float4 b = *reinterpret_cast<const float4*>(a + j * 256 + lane * 4);
            acc[t] += wf[j * 4 + 0] * b.x + wf[j * 4 + 1] * b.y +
                      wf[j * 4 + 2] * b.z + wf[j * 4 + 3] * b.w;
        }
    }
#pragma unroll
    for (int t = 0; t < 10; ++t) {
        float r = wave_red(acc[t]);
        if (lane == 0) nfs[t * 1024 + i] = fmaxf(sv[i] + r, 0.f);
    }
}

// scores of expansion 1 + bd0 + argmin + extraction of a2in/f2in (also writes f2in output)
__global__ void scores1_k(const float* __restrict__ nfs1, const float* __restrict__ g,
                          const float* __restrict__ fs, const float* __restrict__ ajs1,
                          float* __restrict__ s1, float* __restrict__ bd1_out,
                          int* __restrict__ istar_out, float* __restrict__ a2in,
                          float* __restrict__ f2in, float* __restrict__ out_f2in) {
    __shared__ float red[256];
    __shared__ float d[11];
    __shared__ int istar_sh;
    int tid = threadIdx.x;
    for (int t = 0; t < 11; ++t) {
        const float* v = (t < 10) ? (nfs1 + t * 1024) : fs;
        float p = 0.f;
        for (int j = tid * 4; j < tid * 4 + 4; ++j) { float df = v[j] - g[j]; p += df * df; }
        red[tid] = p; __syncthreads();
        for (int s = 128; s; s >>= 1) { if (tid < s) red[tid] += red[tid + s]; __syncthreads(); }
        if (tid == 0) d[t] = red[0] * (1.0f / 1024.0f);
        __syncthreads();
    }
    if (tid == 0) {
        float bd = d[10];  // bd0
        float smin = INFINITY; int im = 0;
        for (int t = 0; t < 10; ++t) {
            float s = bd - d[t];
            s1[t] = s;
            if (s < smin) { smin = s; im = t; }
            if (d[t] < bd) bd = d[t];
        }
        *bd1_out = bd; *istar_out = im; istar_sh = im;
    }
    __syncthreads();
    int im = istar_sh;
    for (int j = tid; j < 1024; j += 256) {
        float a = ajs1[im * 1024 + j], f = nfs1[im * 1024 + j];
        a2in[j] = a; f2in[j] = f; out_f2in[j] = f;
    }
}

// scores of expansion 2 + top-2 select + pa/pfeat/pgoal outputs
__global__ void scores2_k(const float* __restrict__ nfs2, const float* __restrict__ g,
                          const float* __restrict__ fs, const float* __restrict__ ajs1,
                          const float* __restrict__ nfs1, const float* __restrict__ ajs2,
                          const float* __restrict__ a2in, const float* __restrict__ f2in,
                          const float* __restrict__ s1, const float* __restrict__ bd1,
                          const int* __restrict__ istar, float* __restrict__ pa,
                          float* __restrict__ out) {
    __shared__ float red[256];
    __shared__ float d[10];
    __shared__ int sel[2];
    int tid = threadIdx.x;
    for (int t = 0; t < 10; ++t) {
        const float* v = nfs2 + t * 1024;
        float p = 0.f;
        for (int j = tid * 4; j < tid * 4 + 4; ++j) { float df = v[j] - g[j]; p += df * df; }
        red[tid] = p; __syncthreads();
        for (int s = 128; s; s >>= 1) { if (tid < s) red[tid] += red[tid + s]; __syncthreads(); }
        if (tid == 0) d[t] = red[0] * (1.0f / 1024.0f);
        __syncthreads();
    }
    if (tid == 0) {
        float sc[20];
        int im = *istar;
        for (int t = 0; t < 10; ++t) sc[t] = (t == im) ? INFINITY : s1[t];
        float bd = *bd1;
        for (int t = 0; t < 10; ++t) {
            float s = bd - d[t];
            sc[10 + t] = s;
            if (d[t] < bd) bd = d[t];
        }
        int i0 = 0; float m0 = INFINITY;
        for (int t = 0; t < 20; ++t) if (sc[t] < m0) { m0 = sc[t]; i0 = t; }
        int i1 = 0; float m1 = INFINITY;
        for (int t = 0; t < 20; ++t) { if (t == i0) continue; if (sc[t] < m1) { m1 = sc[t]; i1 = t; } }
        sel[0] = i0; sel[1] = i1;
    }
    __syncthreads();
    for (int p = 0; p < 2; ++p) {
        int idx = sel[p];
        for (int j = tid; j < 1024; j += 256) {
            float av, fv;
            if (idx < 10) {
                av = ajs1[idx * 1024 + j] * 0.5f;
                fv = (fs[j] + nfs1[idx * 1024 + j]) * 0.5f;
            } else {
                int t = idx - 10;
                av = (a2in[j] + ajs2[t * 1024 + j]) * (1.0f / 3.0f);
                fv = (fs[j] + f2in[j] + nfs2[t * 1024 + j]) * (1.0f / 3.0f);
            }
            pa[p * 1024 + j] = av;
            out[5980 + p * 1024 + j] = fv;   // pfeat
            out[8028 + p * 1024 + j] = g[j]; // pgoal
        }
    }
}

// pred_actions / pred_verbs / pred_nouns for the 2 selected rows
__global__ void heads_k(const float* __restrict__ We2a, const float* __restrict__ be2a,
                        const float* __restrict__ We2v, const float* __restrict__ be2v,
                        const float* __restrict__ We2n, const float* __restrict__ be2n,
                        const float* __restrict__ pa, float* __restrict__ out) {
    int wave = threadIdx.x >> 6, lane = threadIdx.x & 63;
    int task = blockIdx.x * 4 + wave;
    if (task >= 5980) return;
    int p = (task < 2990) ? 0 : 1;
    int r = task - p * 2990;
    const float* W; const float* b; int outoff, rr;
    if (r < 2513)      { W = We2a; b = be2a; rr = r;        outoff = p * 2513 + rr; }
    else if (r < 2638) { W = We2v; b = be2v; rr = r - 2513; outoff = 5026 + p * 125 + rr; }
    else               { W = We2n; b = be2n; rr = r - 2638; outoff = 5276 + p * 352 + rr; }
    float acc = dotf(W + (size_t)rr * 1024, pa + p * 1024, lane);
    acc = wave_red(acc);
    if (lane == 0) out[outoff] = acc + b[rr];
}

extern "C" void kernel_launch(void* const* d_in, const int* in_sizes, int n_in,
                              void* d_out, int out_size, void* d_ws, size_t ws_size,
                              hipStream_t stream) {
    const float* tsn    = (const float*)d_in[0];
    const float* W_fe   = (const float*)d_in[1];
    const float* b_fe   = (const float*)d_in[2];
    const float* gW_ih0 = (const float*)d_in[3];
    const float* gW_ihR = (const float*)d_in[4];
    // d_in[5] = gW_hh: multiplied by zero hidden state -> never needed
    const float* gb_ih  = (const float*)d_in[6];
    const float* gb_hh  = (const float*)d_in[7];
    const float* rW_ih  = (const float*)d_in[8];
    const float* rW_hh  = (const float*)d_in[9];
    const float* rb_ih  = (const float*)d_in[10];
    const float* rb_hh  = (const float*)d_in[11];
    const float* Wp     = (const float*)d_in[12];
    const float* bp     = (const float*)d_in[13];
    const float* We2a   = (const float*)d_in[14];
    const float* be2a   = (const float*)d_in[15];
    const float* We2v   = (const float*)d_in[16];
    const float* be2v   = (const float*)d_in[17];
    const float* We2n   = (const float*)d_in[18];
    const float* be2n   = (const float*)d_in[19];
    float* out = (float*)d_out;

    float* w = (float*)d_ws;
    float* part  = w + 0;        // 8*1024
    float* maxv  = w + 8192;     // 1024
    float* fs    = w + 9216;     // 1024
    float* hgA   = w + 10240;    // 1024 (final goal g lives here)
    float* hgB   = w + 11264;    // 1024
    float* gx    = w + 12288;    // 4096
    float* ajs1  = w + 16384;    // 10*1024
    float* nfs1  = w + 26624;    // 10*1024
    float* ajs2  = w + 36864;    // 10*1024
    float* nfs2  = w + 47104;    // 10*1024
    float* cc0   = w + 57344;    // 1024
    float* cc1   = w + 58368;    // 1024
    float* sv    = w + 59392;    // 1024
    float* a2in  = w + 60416;    // 1024
    float* f2in  = w + 61440;    // 1024
    float* pa    = w + 62464;    // 2*1024
    float* s1    = w + 64512;    // 10
    float* bd1   = w + 64524;    // 1
    int*   istar = (int*)(w + 64528);

    // 1) fs = max(tsn, axis=0) @ W_fe.T + b_fe
    colmax_part_k<<<8, 256, 0, stream>>>(tsn, part);
    colmax_fin_k<<<4, 256, 0, stream>>>(part, maxv);
    gemv_k<<<256, 256, 0, stream>>>(W_fe, 1024, 1024, maxv, 0, nullptr, 0, b_fe, nullptr, fs, nullptr);
    // cur_action (independent of everything downstream)
    gemv_k<<<629, 256, 0, stream>>>(We2a, 1024, 2513, fs, 0, nullptr, 0, be2a, nullptr, nullptr, out + 11100);

    // 2) goal LSTM: 5 layers, zero states => gates = x @ Wih.T + (gb_ih+gb_hh)
    lstm_fused_k<<<256, 256, 0, stream>>>(gW_ih0, 2048, 0, fs, gb_ih, gb_hh, nullptr, nullptr, nullptr, hgA);
    lstm_fused_k<<<256, 256, 0, stream>>>(gW_ihR + (size_t)0 * 4194304, 1024, 0, hgA, gb_ih + 1 * 4096, gb_hh + 1 * 4096, nullptr, nullptr, nullptr, hgB);
    lstm_fused_k<<<256, 256, 0, stream>>>(gW_ihR + (size_t)1 * 4194304, 1024, 0, hgB, gb_ih + 2 * 4096, gb_hh + 2 * 4096, nullptr, nullptr, nullptr, hgA);
    lstm_fused_k<<<256, 256, 0, stream>>>(gW_ihR + (size_t)2 * 4194304, 1024, 0, hgA, gb_ih + 3 * 4096, gb_hh + 3 * 4096, nullptr, nullptr, nullptr, hgB);
    lstm_fused_k<<<256, 256, 0, stream>>>(gW_ihR + (size_t)3 * 4194304, 1024, 0, hgB, gb_ih + 4 * 4096, gb_hh + 4 * 4096, nullptr, nullptr, nullptr, hgA);
    float* g = hgA;

    // 3) expansion 1: xin = concat(0, fs) -> only cols 1024:2048 of rW_ih
    gemv_k<<<1024, 256, 0, stream>>>(rW_ih, 2048, 4096, nullptr, 0, fs, 1024, rb_ih, rb_hh, gx, nullptr);
    cell0_k<<<4, 256, 0, stream>>>(gx, cc0, ajs1);
    for (int t = 1; t < 10; ++t) {
        float* cin = ((t - 1) & 1) ? cc1 : cc0;
        float* cout = (t & 1) ? cc1 : cc0;
        lstm_fused_k<<<256, 256, 0, stream>>>(rW_hh, 1024, 0, ajs1 + (t - 1) * 1024,
                                              nullptr, nullptr, gx, cin, cout, ajs1 + t * 1024);
    }
    gemv_k<<<256, 256, 0, stream>>>(Wp, 3072, 1024, fs, 0, g, 2048, bp, nullptr, sv, nullptr);
    nfs_k<<<256, 256, 0, stream>>>(Wp, ajs1, sv, nfs1);
    scores1_k<<<1, 256, 0, stream>>>(nfs1, g, fs, ajs1, s1, bd1, istar, a2in, f2in, out + 10076);

    // 4) expansion 2: xin = concat(a2in, f2in)
    gemv_k<<<1024, 256, 0, stream>>>(rW_ih, 2048, 4096, a2in, 0, f2in, 1024, rb_ih, rb_hh, gx, nullptr);
    cell0_k<<<4, 256, 0, stream>>>(gx, cc0, ajs2);
    for (int t = 1; t < 10; ++t) {
        float* cin = ((t - 1) & 1) ? cc1 : cc0;
        float* cout = (t & 1) ? cc1 : cc0;
        lstm_fused_k<<<256, 256, 0, stream>>>(rW_hh, 1024, 0, ajs2 + (t - 1) * 1024,
                                              nullptr, nullptr, gx, cin, cout, ajs2 + t * 1024);
    }
    gemv_k<<<256, 256, 0, stream>>>(Wp, 3072, 1024, f2in, 0, g, 2048, bp, nullptr, sv, nullptr);
    nfs_k<<<256, 256, 0, stream>>>(Wp, ajs2, sv, nfs2);
    scores2_k<<<1, 256, 0, stream>>>(nfs2, g, fs, ajs1, nfs1, ajs2, a2in, f2in, s1, bd1, istar, pa, out);

    // 5) heads
    heads_k<<<1495, 256, 0, stream>>>(We2a, be2a, We2v, be2v, We2n, be2n, pa, out);
}